// Round 7
// baseline (11179.029 us; speedup 1.0000x reference)
//
#include <hip/hip_runtime.h>

#define NPTS 32768
#define BATCH 32
#define SSAMP 2048
#define NF 64

// ---------------------------------------------------------------------------
// FPS distance update matching the XLA-compiled fp32 reference. XLA's JIT
// enables FMA fusion (AllowFPOpFusion::Fast); DAGCombiner on
// ((dx*dx + dy*dy) + dz*dz) fuses operand0 at the inner add and operand1 at
// the outer add:  d = fma(dz,dz, fma(dx,dx, dy*dy)), subs unfused.
// Pinned with explicit fmaf + contract(off) so hipcc can't re-associate.
// Tie-break: strict > keeps the earliest (lowest) index (jnp.argmax).
// ---------------------------------------------------------------------------
__device__ __forceinline__ void fps_upd(float px, float py, float pz, int p,
                                        float qx, float qy, float qz,
                                        float& dist, float& best, int& bidx) {
#pragma clang fp contract(off)
  float dx = px - qx;
  float dy = py - qy;
  float dz = pz - qz;
  float s1 = dy * dy;
  float d = __builtin_fmaf(dz, dz, __builtin_fmaf(dx, dx, s1));
  float nd = fminf(dist, d);
  dist = nd;
  if (nd > best) { best = nd; bidx = p; }
}

// One block (1024 threads) per batch. xyz is [3][NPTS] planes per batch
// (input layout [B,C,N]) -> coalesced float4 streams. dists live in
// registers: 32 per thread (points p = 4*(tid + 1024k)+j).
__global__ void __launch_bounds__(1024) fps_kernel(const float* __restrict__ x,
                                                   float* __restrict__ g) {
  const int b = blockIdx.x;
  const int tid = threadIdx.x;
  const float* xs = x + (size_t)b * 3 * NPTS;
  const float4* xx = reinterpret_cast<const float4*>(xs);
  const float4* xy = reinterpret_cast<const float4*>(xs + NPTS);
  const float4* xz = reinterpret_cast<const float4*>(xs + 2 * NPTS);

  float dist[32];
#pragma unroll
  for (int k = 0; k < 32; ++k) dist[k] = 1e10f;

  __shared__ float bq[3];
  __shared__ float rv[16];
  __shared__ int ri[16];

  float qx = xs[0], qy = xs[NPTS], qz = xs[2 * NPTS];
  float* gb = g + (size_t)b * SSAMP * 3;
  if (tid == 0) { gb[0] = qx; gb[1] = qy; gb[2] = qz; }

  const int wave = tid >> 6;
  const int lane = tid & 63;

  for (int s = 1; s < SSAMP; ++s) {
    float best = -1.0f;
    int bidx = 0;
#pragma unroll
    for (int k = 0; k < 8; ++k) {
      const int vi = tid + k * 1024;
      float4 vx = xx[vi];
      float4 vy = xy[vi];
      float4 vz = xz[vi];
      const int pb = vi * 4;
      fps_upd(vx.x, vy.x, vz.x, pb + 0, qx, qy, qz, dist[k * 4 + 0], best, bidx);
      fps_upd(vx.y, vy.y, vz.y, pb + 1, qx, qy, qz, dist[k * 4 + 1], best, bidx);
      fps_upd(vx.z, vy.z, vz.z, pb + 2, qx, qy, qz, dist[k * 4 + 2], best, bidx);
      fps_upd(vx.w, vy.w, vz.w, pb + 3, qx, qy, qz, dist[k * 4 + 3], best, bidx);
    }
    // 64-lane butterfly argmax, (value desc, index asc) ordering
#pragma unroll
    for (int m = 32; m >= 1; m >>= 1) {
      float ov = __shfl_xor(best, m, 64);
      int oi = __shfl_xor(bidx, m, 64);
      if (ov > best || (ov == best && oi < bidx)) { best = ov; bidx = oi; }
    }
    if (lane == 0) { rv[wave] = best; ri[wave] = bidx; }
    __syncthreads();
    if (wave == 0) {
      // 16-way final reduce in wave 0: lanes 0-15 hold the wave partials.
      float bb = rv[lane & 15];
      int bi = ri[lane & 15];
#pragma unroll
      for (int m = 8; m >= 1; m >>= 1) {
        float v = __shfl_xor(bb, m, 64);
        int i2 = __shfl_xor(bi, m, 64);
        if (v > bb || (v == bb && i2 < bi)) { bb = v; bi = i2; }
      }
      if (tid == 0) {
        float wx2 = xs[bi], wy2 = xs[NPTS + bi], wz2 = xs[2 * NPTS + bi];
        bq[0] = wx2; bq[1] = wy2; bq[2] = wz2;
        float* go = gb + s * 3;
        go[0] = wx2; go[1] = wy2; go[2] = wz2;
      }
    }
    __syncthreads();
    qx = bq[0]; qy = bq[1]; qz = bq[2];
  }
}

// Reduce sampled points: Sum(g), Sum(g g^T) in doubles -> 9 accumulators.
__global__ void reduce_g_kernel(const float* __restrict__ g,
                                double* __restrict__ acc) {
  const int total = BATCH * SSAMP;
  double a0 = 0, a1 = 0, a2 = 0, a3 = 0, a4 = 0, a5 = 0, a6 = 0, a7 = 0, a8 = 0;
  for (int i = blockIdx.x * blockDim.x + threadIdx.x; i < total;
       i += gridDim.x * blockDim.x) {
    double dx = (double)g[i * 3 + 0];
    double dy = (double)g[i * 3 + 1];
    double dz = (double)g[i * 3 + 2];
    a0 += dx; a1 += dy; a2 += dz;
    a3 += dx * dx; a4 += dy * dy; a5 += dz * dz;
    a6 += dx * dy; a7 += dx * dz; a8 += dy * dz;
  }
#pragma unroll
  for (int m = 32; m >= 1; m >>= 1) {
    a0 += __shfl_xor(a0, m, 64);
    a1 += __shfl_xor(a1, m, 64);
    a2 += __shfl_xor(a2, m, 64);
    a3 += __shfl_xor(a3, m, 64);
    a4 += __shfl_xor(a4, m, 64);
    a5 += __shfl_xor(a5, m, 64);
    a6 += __shfl_xor(a6, m, 64);
    a7 += __shfl_xor(a7, m, 64);
    a8 += __shfl_xor(a8, m, 64);
  }
  if ((threadIdx.x & 63) == 0) {
    atomicAdd(&acc[0], a0); atomicAdd(&acc[1], a1); atomicAdd(&acc[2], a2);
    atomicAdd(&acc[3], a3); atomicAdd(&acc[4], a4); atomicAdd(&acc[5], a5);
    atomicAdd(&acc[6], a6); atomicAdd(&acc[7], a7); atomicAdd(&acc[8], a8);
  }
}

// BN stats in closed form: h = w_f . g + b_f is linear in g, so
// mu_f and var_f follow from Sum(g), Sum(g g^T). A = gamma*rsqrt(var+eps),
// C = beta - mu*A  (BN reduces to y = A*h + C).
__global__ void bnstats_kernel(const double* __restrict__ acc,
                               const float* __restrict__ w,
                               const float* __restrict__ bias,
                               const float* __restrict__ gamma,
                               const float* __restrict__ beta,
                               float* __restrict__ AC) {
  int f = threadIdx.x;
  if (f >= NF) return;
  const double n = (double)(BATCH * SSAMP);
  double w0 = w[f * 3 + 0], w1 = w[f * 3 + 1], w2 = w[f * 3 + 2];
  double bf = bias[f];
  double m1x = acc[0] / n, m1y = acc[1] / n, m1z = acc[2] / n;
  double wdotm = w0 * m1x + w1 * m1y + w2 * m1z;
  double mu = wdotm + bf;
  double e2 = (w0 * w0 * acc[3] + w1 * w1 * acc[4] + w2 * w2 * acc[5] +
               2.0 * (w0 * w1 * acc[6] + w0 * w2 * acc[7] + w1 * w2 * acc[8])) / n +
              2.0 * bf * wdotm + bf * bf;
  double var = e2 - mu * mu;
  if (var < 0) var = 0;
  double A = (double)gamma[f] / sqrt(var + 1e-5);
  AC[f] = (float)A;
  AC[NF + f] = (float)((double)beta[f] - mu * A);
}

// Per batch: recompute h from g (LDS-staged), BN+LeakyReLU, per-(b,f)
// mean/std over S (ddof=1), final affine. One block per batch,
// threads = 64 features x 16 s-groups.
__global__ void __launch_bounds__(1024) finalize_kernel(
    const float* __restrict__ g, const float* __restrict__ w,
    const float* __restrict__ bias, const float* __restrict__ AC,
    const float* __restrict__ alpha, const float* __restrict__ beta,
    float* __restrict__ out) {
  const int b = blockIdx.x;
  const int f = threadIdx.x & 63;
  const int j = threadIdx.x >> 6;  // 0..15

  __shared__ float gs[SSAMP * 3];
  __shared__ float red[2][16][NF];
  __shared__ float mb[NF], ib[NF];

  const float* gbase = g + (size_t)b * SSAMP * 3;
  for (int i = threadIdx.x; i < SSAMP * 3; i += 1024) gs[i] = gbase[i];
  __syncthreads();

  const float w0 = w[f * 3 + 0], w1 = w[f * 3 + 1], w2 = w[f * 3 + 2];
  const float bf = bias[f];
  const float A = AC[f], C = AC[NF + f];

  float sum = 0.f, sumsq = 0.f;
  for (int t = 0; t < SSAMP / 16; ++t) {
    int sidx = j * (SSAMP / 16) + t;
    float gx = gs[sidx * 3 + 0], gy = gs[sidx * 3 + 1], gz = gs[sidx * 3 + 2];
    float h = w0 * gx + w1 * gy + w2 * gz + bf;
    float y = A * h + C;
    y = (y >= 0.f) ? y : 0.01f * y;
    sum += y;
    sumsq += y * y;
  }
  red[0][j][f] = sum;
  red[1][j][f] = sumsq;
  __syncthreads();
  if (threadIdx.x < NF) {
    float ts = 0.f, tq = 0.f;
    for (int jj = 0; jj < 16; ++jj) {
      ts += red[0][jj][threadIdx.x];
      tq += red[1][jj][threadIdx.x];
    }
    float m = ts / (float)SSAMP;
    float var = (tq - (float)SSAMP * m * m) / (float)(SSAMP - 1);
    if (var < 0.f) var = 0.f;
    float sd = sqrtf(var);
    mb[threadIdx.x] = m;
    ib[threadIdx.x] = 1.f / (sd + 1e-5f);
  }
  __syncthreads();

  const float m = mb[f], inv = ib[f];
  const float al = alpha[f], be = beta[f];
  float* ob = out + (size_t)b * SSAMP * NF;
  for (int t = 0; t < SSAMP / 16; ++t) {
    int sidx = j * (SSAMP / 16) + t;
    float gx = gs[sidx * 3 + 0], gy = gs[sidx * 3 + 1], gz = gs[sidx * 3 + 2];
    float h = w0 * gx + w1 * gy + w2 * gz + bf;
    float y = A * h + C;
    y = (y >= 0.f) ? y : 0.01f * y;
    ob[(size_t)sidx * NF + f] = al * ((y - m) * inv) + be;
  }
}

extern "C" void kernel_launch(void* const* d_in, const int* in_sizes, int n_in,
                              void* d_out, int out_size, void* d_ws, size_t ws_size,
                              hipStream_t stream) {
  const float* x = (const float*)d_in[0];
  const float* conv_w = (const float*)d_in[1];
  const float* conv_b = (const float*)d_in[2];
  const float* bn_gamma = (const float*)d_in[3];
  const float* bn_beta = (const float*)d_in[4];
  const float* alpha = (const float*)d_in[5];
  const float* beta = (const float*)d_in[6];
  float* out = (float*)d_out;

  char* ws = (char*)d_ws;
  float* g = (float*)ws;                      // BATCH*SSAMP*3 floats = 786432 B
  double* acc = (double*)(ws + 786432);       // 9 doubles = 72 B
  float* AC = (float*)(ws + 786432 + 128);    // 2*NF floats

  hipLaunchKernelGGL(fps_kernel, dim3(BATCH), dim3(1024), 0, stream, x, g);
  hipMemsetAsync(acc, 0, 9 * sizeof(double), stream);
  hipLaunchKernelGGL(reduce_g_kernel, dim3(64), dim3(256), 0, stream, g, acc);
  hipLaunchKernelGGL(bnstats_kernel, dim3(1), dim3(64), 0, stream, acc,
                     conv_w, conv_b, bn_gamma, bn_beta, AC);
  hipLaunchKernelGGL(finalize_kernel, dim3(BATCH), dim3(1024), 0, stream, g,
                     conv_w, conv_b, AC, alpha, beta, out);
}

// Round 12
// 10234.668 us; speedup vs baseline: 1.0923x; 1.0923x over previous
//
#include <hip/hip_runtime.h>

#define NPTS 32768
#define BATCH 32
#define SSAMP 2048
#define NF 64
#define NBLK 4               // blocks per batch (must divide NPTS; grid = 32*NBLK <= 256)
#define CHUNK (NPTS / NBLK)  // 8192 points per block
#define AGENT __HIP_MEMORY_SCOPE_AGENT

// ---------------------------------------------------------------------------
// FPS distance update matching the XLA-compiled fp32 reference (verified R7):
// d = fma(dz,dz, fma(dx,dx, dy*dy)), subs unfused, fminf min-update,
// strict > keeps earliest index. Also tracks the winning point's coords.
// ---------------------------------------------------------------------------
__device__ __forceinline__ void fps_upd(float px, float py, float pz, int p,
                                        float qx, float qy, float qz,
                                        float& dist, float& best, int& bidx,
                                        float& bx, float& by, float& bz) {
#pragma clang fp contract(off)
  float dx = px - qx;
  float dy = py - qy;
  float dz = pz - qz;
  float s1 = dy * dy;
  float d = __builtin_fmaf(dz, dz, __builtin_fmaf(dx, dx, s1));
  float nd = fminf(dist, d);
  dist = nd;
  if (nd > best) { best = nd; bidx = p; bx = px; by = py; bz = pz; }
}

// 128 blocks: batch b = blockIdx%32, chunk blk = blockIdx/32. Each thread
// owns 8 points fully register-resident (24 VGPR xyz + 8 VGPR dist) ->
// zero global re-streaming per step. Per-step cross-block rendezvous:
// the unique owner thread publishes {val,idx,x,y,z} (relaxed agent stores)
// then flag=s (release agent); lanes 0..3 of wave 0 poll flags with >=
// (max skew 1 step) and read parity-(s&1) double-buffered slots.
__global__ void __launch_bounds__(1024) fps_kernel(const float* __restrict__ x,
                                                   float* __restrict__ g,
                                                   int* __restrict__ flags,
                                                   float* __restrict__ slots) {
  const int gb = blockIdx.x;
  const int b = gb & 31;
  const int blk = gb >> 5;
  const int tid = threadIdx.x;
  const int wave = tid >> 6;
  const int lane = tid & 63;

  const float* xs = x + (size_t)b * 3 * NPTS;
  const float4* xx = reinterpret_cast<const float4*>(xs) + blk * (CHUNK / 4);
  const float4* xy = reinterpret_cast<const float4*>(xs + NPTS) + blk * (CHUNK / 4);
  const float4* xz = reinterpret_cast<const float4*>(xs + 2 * NPTS) + blk * (CHUNK / 4);

  // Register-resident chunk: 2 float4 per plane per thread.
  float4 PX0 = xx[tid], PX1 = xx[tid + 1024];
  float4 PY0 = xy[tid], PY1 = xy[tid + 1024];
  float4 PZ0 = xz[tid], PZ1 = xz[tid + 1024];

  float dist[8];
#pragma unroll
  for (int k = 0; k < 8; ++k) dist[k] = 1e10f;

  __shared__ float rv[16];
  __shared__ int ri[16];
  __shared__ float bq[3];
  __shared__ int wi;

  float qx = xs[0], qy = xs[NPTS], qz = xs[2 * NPTS];
  float* gb_out = g + (size_t)b * SSAMP * 3;
  if (blk == 0 && tid == 0) { gb_out[0] = qx; gb_out[1] = qy; gb_out[2] = qz; }

  int* myflags = flags + b * 32;  // 4 ints used, 128B line per batch
  const int pb0 = blk * CHUNK + 4 * tid;
  const int pb1 = blk * CHUNK + 4 * (tid + 1024);

  for (int s = 1; s < SSAMP; ++s) {
    float best = -1.0f;
    int bidx = 0;
    float bx = 0.f, by = 0.f, bz = 0.f;

    fps_upd(PX0.x, PY0.x, PZ0.x, pb0 + 0, qx, qy, qz, dist[0], best, bidx, bx, by, bz);
    fps_upd(PX0.y, PY0.y, PZ0.y, pb0 + 1, qx, qy, qz, dist[1], best, bidx, bx, by, bz);
    fps_upd(PX0.z, PY0.z, PZ0.z, pb0 + 2, qx, qy, qz, dist[2], best, bidx, bx, by, bz);
    fps_upd(PX0.w, PY0.w, PZ0.w, pb0 + 3, qx, qy, qz, dist[3], best, bidx, bx, by, bz);
    fps_upd(PX1.x, PY1.x, PZ1.x, pb1 + 0, qx, qy, qz, dist[4], best, bidx, bx, by, bz);
    fps_upd(PX1.y, PY1.y, PZ1.y, pb1 + 1, qx, qy, qz, dist[5], best, bidx, bx, by, bz);
    fps_upd(PX1.z, PY1.z, PZ1.z, pb1 + 2, qx, qy, qz, dist[6], best, bidx, bx, by, bz);
    fps_upd(PX1.w, PY1.w, PZ1.w, pb1 + 3, qx, qy, qz, dist[7], best, bidx, bx, by, bz);

    // 64-lane butterfly argmax on (val desc, idx asc).
    float v = best;
    int i = bidx;
#pragma unroll
    for (int m = 32; m >= 1; m >>= 1) {
      float ov = __shfl_xor(v, m, 64);
      int oi = __shfl_xor(i, m, 64);
      if (ov > v || (ov == v && oi < i)) { v = ov; i = oi; }
    }
    if (lane == 0) { rv[wave] = v; ri[wave] = i; }
    __syncthreads();
    if (wave == 0) {
      float bb = rv[lane & 15];
      int bi = ri[lane & 15];
#pragma unroll
      for (int m = 8; m >= 1; m >>= 1) {
        float ov = __shfl_xor(bb, m, 64);
        int oi = __shfl_xor(bi, m, 64);
        if (ov > bb || (ov == bb && oi < bi)) { bb = ov; bi = oi; }
      }
      if (lane == 0) { wi = bi; }
    }
    __syncthreads();

    // Unique owner (disjoint point sets per thread) publishes to this
    // block's parity slot, then releases its flag with the step number.
    if (bidx == wi) {
      int* slot = (int*)(slots + ((size_t)(b * NBLK + blk) * 2 + (s & 1)) * 8);
      __hip_atomic_store(slot + 0, __float_as_int(best), __ATOMIC_RELAXED, AGENT);
      __hip_atomic_store(slot + 1, bidx, __ATOMIC_RELAXED, AGENT);
      __hip_atomic_store(slot + 2, __float_as_int(bx), __ATOMIC_RELAXED, AGENT);
      __hip_atomic_store(slot + 3, __float_as_int(by), __ATOMIC_RELAXED, AGENT);
      __hip_atomic_store(slot + 4, __float_as_int(bz), __ATOMIC_RELAXED, AGENT);
      __hip_atomic_store(&myflags[blk], s, __ATOMIC_RELEASE, AGENT);
    }

    // Lanes 0..3 of wave 0 poll the 4 flags (>= s: skew is at most 1 step
    // and slots are parity double-buffered; poison 0xAAAAAAAA < 0 never
    // matches), then combine the 4 chunk winners.
    if (wave == 0 && lane < 4) {
      while (__hip_atomic_load(&myflags[lane], __ATOMIC_ACQUIRE, AGENT) < s) {}
      const int* slot = (const int*)(slots + ((size_t)(b * NBLK + lane) * 2 + (s & 1)) * 8);
      float cv = __int_as_float(__hip_atomic_load(slot + 0, __ATOMIC_RELAXED, AGENT));
      int ci = __hip_atomic_load(slot + 1, __ATOMIC_RELAXED, AGENT);
      float cx = __int_as_float(__hip_atomic_load(slot + 2, __ATOMIC_RELAXED, AGENT));
      float cy = __int_as_float(__hip_atomic_load(slot + 3, __ATOMIC_RELAXED, AGENT));
      float cz = __int_as_float(__hip_atomic_load(slot + 4, __ATOMIC_RELAXED, AGENT));
#pragma unroll
      for (int m = 1; m <= 2; m <<= 1) {
        float ov = __shfl_xor(cv, m, 64);
        int oi = __shfl_xor(ci, m, 64);
        float ox = __shfl_xor(cx, m, 64);
        float oy = __shfl_xor(cy, m, 64);
        float oz = __shfl_xor(cz, m, 64);
        if (ov > cv || (ov == cv && oi < ci)) { cv = ov; ci = oi; cx = ox; cy = oy; cz = oz; }
      }
      if (lane == 0) {
        bq[0] = cx; bq[1] = cy; bq[2] = cz;
        if (blk == 0) {
          float* go = gb_out + s * 3;
          go[0] = cx; go[1] = cy; go[2] = cz;
        }
      }
    }
    __syncthreads();
    qx = bq[0]; qy = bq[1]; qz = bq[2];
  }
}

// Reduce sampled points: Sum(g), Sum(g g^T) in doubles -> 9 accumulators.
__global__ void reduce_g_kernel(const float* __restrict__ g,
                                double* __restrict__ acc) {
  const int total = BATCH * SSAMP;
  double a0 = 0, a1 = 0, a2 = 0, a3 = 0, a4 = 0, a5 = 0, a6 = 0, a7 = 0, a8 = 0;
  for (int i = blockIdx.x * blockDim.x + threadIdx.x; i < total;
       i += gridDim.x * blockDim.x) {
    double dx = (double)g[i * 3 + 0];
    double dy = (double)g[i * 3 + 1];
    double dz = (double)g[i * 3 + 2];
    a0 += dx; a1 += dy; a2 += dz;
    a3 += dx * dx; a4 += dy * dy; a5 += dz * dz;
    a6 += dx * dy; a7 += dx * dz; a8 += dy * dz;
  }
#pragma unroll
  for (int m = 32; m >= 1; m >>= 1) {
    a0 += __shfl_xor(a0, m, 64);
    a1 += __shfl_xor(a1, m, 64);
    a2 += __shfl_xor(a2, m, 64);
    a3 += __shfl_xor(a3, m, 64);
    a4 += __shfl_xor(a4, m, 64);
    a5 += __shfl_xor(a5, m, 64);
    a6 += __shfl_xor(a6, m, 64);
    a7 += __shfl_xor(a7, m, 64);
    a8 += __shfl_xor(a8, m, 64);
  }
  if ((threadIdx.x & 63) == 0) {
    atomicAdd(&acc[0], a0); atomicAdd(&acc[1], a1); atomicAdd(&acc[2], a2);
    atomicAdd(&acc[3], a3); atomicAdd(&acc[4], a4); atomicAdd(&acc[5], a5);
    atomicAdd(&acc[6], a6); atomicAdd(&acc[7], a7); atomicAdd(&acc[8], a8);
  }
}

// BN stats in closed form from Sum(g), Sum(g g^T): y = A*h + C.
__global__ void bnstats_kernel(const double* __restrict__ acc,
                               const float* __restrict__ w,
                               const float* __restrict__ bias,
                               const float* __restrict__ gamma,
                               const float* __restrict__ beta,
                               float* __restrict__ AC) {
  int f = threadIdx.x;
  if (f >= NF) return;
  const double n = (double)(BATCH * SSAMP);
  double w0 = w[f * 3 + 0], w1 = w[f * 3 + 1], w2 = w[f * 3 + 2];
  double bf = bias[f];
  double m1x = acc[0] / n, m1y = acc[1] / n, m1z = acc[2] / n;
  double wdotm = w0 * m1x + w1 * m1y + w2 * m1z;
  double mu = wdotm + bf;
  double e2 = (w0 * w0 * acc[3] + w1 * w1 * acc[4] + w2 * w2 * acc[5] +
               2.0 * (w0 * w1 * acc[6] + w0 * w2 * acc[7] + w1 * w2 * acc[8])) / n +
              2.0 * bf * wdotm + bf * bf;
  double var = e2 - mu * mu;
  if (var < 0) var = 0;
  double A = (double)gamma[f] / sqrt(var + 1e-5);
  AC[f] = (float)A;
  AC[NF + f] = (float)((double)beta[f] - mu * A);
}

// Per batch: recompute h from g (LDS-staged), BN+LeakyReLU, per-(b,f)
// mean/std over S (ddof=1), final affine.
__global__ void __launch_bounds__(1024) finalize_kernel(
    const float* __restrict__ g, const float* __restrict__ w,
    const float* __restrict__ bias, const float* __restrict__ AC,
    const float* __restrict__ alpha, const float* __restrict__ beta,
    float* __restrict__ out) {
  const int b = blockIdx.x;
  const int f = threadIdx.x & 63;
  const int j = threadIdx.x >> 6;  // 0..15

  __shared__ float gs[SSAMP * 3];
  __shared__ float red[2][16][NF];
  __shared__ float mb[NF], ib[NF];

  const float* gbase = g + (size_t)b * SSAMP * 3;
  for (int i = threadIdx.x; i < SSAMP * 3; i += 1024) gs[i] = gbase[i];
  __syncthreads();

  const float w0 = w[f * 3 + 0], w1 = w[f * 3 + 1], w2 = w[f * 3 + 2];
  const float bf = bias[f];
  const float A = AC[f], C = AC[NF + f];

  float sum = 0.f, sumsq = 0.f;
  for (int t = 0; t < SSAMP / 16; ++t) {
    int sidx = j * (SSAMP / 16) + t;
    float gx = gs[sidx * 3 + 0], gy = gs[sidx * 3 + 1], gz = gs[sidx * 3 + 2];
    float h = w0 * gx + w1 * gy + w2 * gz + bf;
    float y = A * h + C;
    y = (y >= 0.f) ? y : 0.01f * y;
    sum += y;
    sumsq += y * y;
  }
  red[0][j][f] = sum;
  red[1][j][f] = sumsq;
  __syncthreads();
  if (threadIdx.x < NF) {
    float ts = 0.f, tq = 0.f;
    for (int jj = 0; jj < 16; ++jj) {
      ts += red[0][jj][threadIdx.x];
      tq += red[1][jj][threadIdx.x];
    }
    float m = ts / (float)SSAMP;
    float var = (tq - (float)SSAMP * m * m) / (float)(SSAMP - 1);
    if (var < 0.f) var = 0.f;
    float sd = sqrtf(var);
    mb[threadIdx.x] = m;
    ib[threadIdx.x] = 1.f / (sd + 1e-5f);
  }
  __syncthreads();

  const float m = mb[f], inv = ib[f];
  const float al = alpha[f], be = beta[f];
  float* ob = out + (size_t)b * SSAMP * NF;
  for (int t = 0; t < SSAMP / 16; ++t) {
    int sidx = j * (SSAMP / 16) + t;
    float gx = gs[sidx * 3 + 0], gy = gs[sidx * 3 + 1], gz = gs[sidx * 3 + 2];
    float h = w0 * gx + w1 * gy + w2 * gz + bf;
    float y = A * h + C;
    y = (y >= 0.f) ? y : 0.01f * y;
    ob[(size_t)sidx * NF + f] = al * ((y - m) * inv) + be;
  }
}

extern "C" void kernel_launch(void* const* d_in, const int* in_sizes, int n_in,
                              void* d_out, int out_size, void* d_ws, size_t ws_size,
                              hipStream_t stream) {
  const float* x = (const float*)d_in[0];
  const float* conv_w = (const float*)d_in[1];
  const float* conv_b = (const float*)d_in[2];
  const float* bn_gamma = (const float*)d_in[3];
  const float* bn_beta = (const float*)d_in[4];
  const float* alpha = (const float*)d_in[5];
  const float* beta = (const float*)d_in[6];
  float* out = (float*)d_out;

  char* ws = (char*)d_ws;
  float* g = (float*)ws;                       // 786432 B
  double* acc = (double*)(ws + 786432);        // 72 B (128 B slot)
  float* AC = (float*)(ws + 786432 + 128);     // 512 B
  int* flags = (int*)(ws + 787456);            // 32 batches x 32 ints = 4096 B
  float* slots = (float*)(ws + 791552);        // 128 x 2 parity x 8 f32 = 8192 B

  hipLaunchKernelGGL(fps_kernel, dim3(BATCH * NBLK), dim3(1024), 0, stream,
                     x, g, flags, slots);
  hipMemsetAsync(acc, 0, 9 * sizeof(double), stream);
  hipLaunchKernelGGL(reduce_g_kernel, dim3(64), dim3(256), 0, stream, g, acc);
  hipLaunchKernelGGL(bnstats_kernel, dim3(1), dim3(64), 0, stream, acc,
                     conv_w, conv_b, bn_gamma, bn_beta, AC);
  hipLaunchKernelGGL(finalize_kernel, dim3(BATCH), dim3(1024), 0, stream, g,
                     conv_w, conv_b, AC, alpha, beta, out);
}